// Round 3
// baseline (338.400 us; speedup 1.0000x reference)
//
#include <hip/hip_runtime.h>
#include <hip/hip_bf16.h>

#define HDIM 128
#define H3   384
#define RDIM 20
#define NPB  16   // nodes per block (node MLP)
#define CHNK 32   // edge chunk per block in reduce kernel

typedef unsigned short u16;

__device__ __forceinline__ float bf2f(u16 u) {
    union { unsigned int i; float f; } x;
    x.i = ((unsigned int)u) << 16;
    return x.f;
}
__device__ __forceinline__ u16 f2bf(float f) {
    __hip_bfloat16 h = __float2bfloat16(f);   // round-to-nearest
    return *(u16*)&h;
}

// -------- Kernel 1: per-node MLP  P = silu(s@W1+b1) @ W2 + b2 -> bf16 --------
__global__ __launch_bounds__(128) void node_mlp_kernel(
    const float* __restrict__ s, const float* __restrict__ W1,
    const float* __restrict__ b1, const float* __restrict__ W2,
    const float* __restrict__ b2, u16* __restrict__ P, int N)
{
    __shared__ float sS[NPB][HDIM];
    __shared__ float sH[NPB][HDIM];
    const int t  = threadIdx.x;
    const int n0 = blockIdx.x * NPB;

    #pragma unroll
    for (int n = 0; n < NPB; ++n) {
        int node = n0 + n;
        sS[n][t] = (node < N) ? s[(size_t)node * HDIM + t] : 0.f;
    }
    __syncthreads();

    float acc[NPB];
    #pragma unroll
    for (int n = 0; n < NPB; ++n) acc[n] = 0.f;
    for (int k = 0; k < HDIM; ++k) {
        float w = W1[k * HDIM + t];
        #pragma unroll
        for (int n = 0; n < NPB; ++n) acc[n] += sS[n][k] * w;
    }
    float bb = b1[t];
    #pragma unroll
    for (int n = 0; n < NPB; ++n) {
        float z = acc[n] + bb;
        sH[n][t] = z / (1.f + __expf(-z));   // silu
    }
    __syncthreads();

    float a0[NPB], a1[NPB], a2[NPB];
    #pragma unroll
    for (int n = 0; n < NPB; ++n) { a0[n] = 0.f; a1[n] = 0.f; a2[n] = 0.f; }
    for (int k2 = 0; k2 < HDIM / 2; ++k2) {
        float2 hv[NPB];
        #pragma unroll
        for (int n = 0; n < NPB; ++n) hv[n] = ((const float2*)sH[n])[k2];
        #pragma unroll
        for (int kk = 0; kk < 2; ++kk) {
            int k = 2 * k2 + kk;
            float w0 = W2[k * H3 + t];
            float w1 = W2[k * H3 + t + 128];
            float w2 = W2[k * H3 + t + 256];
            #pragma unroll
            for (int n = 0; n < NPB; ++n) {
                float h = kk ? hv[n].y : hv[n].x;
                a0[n] += h * w0;
                a1[n] += h * w1;
                a2[n] += h * w2;
            }
        }
    }
    float c0 = b2[t], c1 = b2[t + 128], c2 = b2[t + 256];
    #pragma unroll
    for (int n = 0; n < NPB; ++n) {
        int node = n0 + n;
        if (node < N) {
            size_t base = (size_t)node * H3;
            P[base + t]       = f2bf(a0[n] + c0);
            P[base + t + 128] = f2bf(a1[n] + c1);
            P[base + t + 256] = f2bf(a2[n] + c2);
        }
    }
}

// -------- v fp32 -> bf16 copy --------
__global__ void vconv_kernel(const float* __restrict__ v, u16* __restrict__ Vb, int nquads)
{
    int idx = blockIdx.x * 256 + threadIdx.x;
    int stride = gridDim.x * 256;
    for (; idx < nquads; idx += stride) {
        float4 f = ((const float4*)v)[idx];
        ushort4 o;
        o.x = f2bf(f.x); o.y = f2bf(f.y); o.z = f2bf(f.z); o.w = f2bf(f.w);
        ((ushort4*)Vb)[idx] = o;
    }
}

// -------- CSR build --------
__global__ void hist_kernel(const int* __restrict__ eidx, int* __restrict__ counts, int E)
{
    int e = blockIdx.x * 256 + threadIdx.x;
    if (e < E) atomicAdd(&counts[eidx[e]], 1);
}

__global__ __launch_bounds__(1024) void scan_kernel(
    const int* __restrict__ counts, int* __restrict__ rstart,
    int* __restrict__ cursor, int N)
{
    __shared__ int part[1024];
    const int t = threadIdx.x;
    const int C = 20;
    int loc[C];
    int s = 0;
    #pragma unroll
    for (int q = 0; q < C; ++q) {
        int idx = t * C + q;
        int c = (idx < N) ? counts[idx] : 0;
        loc[q] = s; s += c;
    }
    part[t] = s;
    __syncthreads();
    for (int off = 1; off < 1024; off <<= 1) {
        int vv = (t >= off) ? part[t - off] : 0;
        __syncthreads();
        part[t] += vv;
        __syncthreads();
    }
    int boff = (t > 0) ? part[t - 1] : 0;
    #pragma unroll
    for (int q = 0; q < C; ++q) {
        int idx = t * C + q;
        if (idx < N) {
            int st = boff + loc[q];
            rstart[idx] = st;
            cursor[idx] = st;
        }
    }
    if (t == 1023) rstart[N] = part[1023];
}

__global__ void scatter_kernel(const int* __restrict__ eidx, int* __restrict__ cursor,
                               int* __restrict__ eord, int E)
{
    int e = blockIdx.x * 256 + threadIdx.x;
    if (e < E) {
        int i = eidx[e];
        int pos = atomicAdd(&cursor[i], 1);
        eord[pos] = e;
    }
}

// -------- Kernel 2: node-centric gather-reduce (bf16 gathers, pipelined) --------
__global__ __launch_bounds__(128) void reduce_kernel(
    const int* __restrict__ rstart, const int* __restrict__ eord,
    const float* __restrict__ rbf, const float* __restrict__ cutoff,
    const float* __restrict__ evec, const float* __restrict__ Wr,
    const float* __restrict__ br, const u16* __restrict__ Pb,
    const u16* __restrict__ Vb, const int* __restrict__ eidx,
    float* __restrict__ ds, float* __restrict__ dv, int E)
{
    const int t = threadIdx.x;
    const int i = blockIdx.x;

    // Wr columns for this thread, held in registers for the whole row
    float wr0[RDIM], wr1[RDIM], wr2[RDIM];
    #pragma unroll
    for (int k = 0; k < RDIM; ++k) {
        wr0[k] = Wr[k * H3 + t];
        wr1[k] = Wr[k * H3 + t + 128];
        wr2[k] = Wr[k * H3 + t + 256];
    }
    float br0 = br[t], br1 = br[t + 128], br2 = br[t + 256];

    int beg = rstart[i], end = rstart[i + 1];
    float accs = 0.f, accx = 0.f, accy = 0.f, accz = 0.f;

    __shared__ int   sE[CHNK], sJ[CHNK];
    __shared__ float sCut[CHNK], sVx[CHNK], sVy[CHNK], sVz[CHNK];
    __shared__ __attribute__((aligned(16))) float sRbf[CHNK][RDIM];

    for (int c0 = beg; c0 < end; c0 += CHNK) {
        int cnt = min(CHNK, end - c0);
        __syncthreads();
        if (t < cnt) {
            int e = eord[c0 + t];
            sE[t]   = e;
            sJ[t]   = eidx[E + e];
            sCut[t] = cutoff[e];
            sVx[t]  = evec[3 * e];
            sVy[t]  = evec[3 * e + 1];
            sVz[t]  = evec[3 * e + 2];
        }
        __syncthreads();
        for (int x = t; x < cnt * RDIM; x += 128) {
            int n = x / RDIM, k = x - n * RDIM;
            sRbf[n][k] = rbf[(size_t)sE[n] * RDIM + k];
        }
        __syncthreads();

        // prologue: prefetch gathers for q=0
        u16 cpss, cpsv, cpvv, cvx, cvy, cvz;
        {
            size_t pj = (size_t)sJ[0] * H3;
            cpss = Pb[pj + t]; cpsv = Pb[pj + 128 + t]; cpvv = Pb[pj + 256 + t];
            cvx  = Vb[pj + t]; cvy  = Vb[pj + 128 + t]; cvz  = Vb[pj + 256 + t];
        }
        for (int q = 0; q < cnt; ++q) {
            u16 npss = 0, npsv = 0, npvv = 0, nvx = 0, nvy = 0, nvz = 0;
            if (q + 1 < cnt) {
                size_t pj = (size_t)sJ[q + 1] * H3;
                npss = Pb[pj + t]; npsv = Pb[pj + 128 + t]; npvv = Pb[pj + 256 + t];
                nvx  = Vb[pj + t]; nvy  = Vb[pj + 128 + t]; nvz  = Vb[pj + 256 + t];
            }
            // rbf dot from LDS (broadcast reads)
            const float4* r4 = (const float4*)sRbf[q];
            float w0 = 0.f, w1 = 0.f, w2 = 0.f;
            #pragma unroll
            for (int k4 = 0; k4 < 5; ++k4) {
                float4 r = r4[k4];
                w0 += r.x * wr0[4*k4+0] + r.y * wr0[4*k4+1] + r.z * wr0[4*k4+2] + r.w * wr0[4*k4+3];
                w1 += r.x * wr1[4*k4+0] + r.y * wr1[4*k4+1] + r.z * wr1[4*k4+2] + r.w * wr1[4*k4+3];
                w2 += r.x * wr2[4*k4+0] + r.y * wr2[4*k4+1] + r.z * wr2[4*k4+2] + r.w * wr2[4*k4+3];
            }
            float cu = sCut[q];
            float ex = sVx[q], ey = sVy[q], ez = sVz[q];
            float xss = (w0 + br0) * cu * bf2f(cpss);
            float xsv = (w1 + br1) * cu * bf2f(cpsv);
            float xvv = (w2 + br2) * cu * bf2f(cpvv);
            float inner = bf2f(cvx) * ex + bf2f(cvy) * ey + bf2f(cvz) * ez;
            float coef  = xsv + inner * xvv;
            accs += xss;
            accx += coef * ex;
            accy += coef * ey;
            accz += coef * ez;
            cpss = npss; cpsv = npsv; cpvv = npvv;
            cvx = nvx; cvy = nvy; cvz = nvz;
        }
    }

    ds[(size_t)i * HDIM + t] = accs;
    size_t dvi = (size_t)i * H3;
    dv[dvi + t]       = accx;
    dv[dvi + 128 + t] = accy;
    dv[dvi + 256 + t] = accz;
}

extern "C" void kernel_launch(void* const* d_in, const int* in_sizes, int n_in,
                              void* d_out, int out_size, void* d_ws, size_t ws_size,
                              hipStream_t stream)
{
    const float* s    = (const float*)d_in[0];
    const float* v    = (const float*)d_in[1];
    const float* rbf  = (const float*)d_in[2];
    const float* cut  = (const float*)d_in[3];
    const float* evec = (const float*)d_in[4];
    const float* W1   = (const float*)d_in[5];
    const float* b1   = (const float*)d_in[6];
    const float* W2   = (const float*)d_in[7];
    const float* b2   = (const float*)d_in[8];
    const float* Wr   = (const float*)d_in[9];
    const float* br   = (const float*)d_in[10];
    const int*   eidx = (const int*)d_in[11];

    const int N = in_sizes[0] / HDIM;   // 20000
    const int E = in_sizes[3];          // 400000

    float* out = (float*)d_out;
    float* ds  = out;                      // [N, H]
    float* dv  = out + (size_t)N * HDIM;   // [N, 3, H]

    // workspace layout (256B aligned chunks)
    char* w = (char*)d_ws;
    u16* P  = (u16*)w;                     w += ((size_t)N * H3 * 2 + 255) / 256 * 256;
    u16* Vb = (u16*)w;                     w += ((size_t)N * H3 * 2 + 255) / 256 * 256;
    int* counts = (int*)w;                 w += ((size_t)N * 4 + 255) / 256 * 256;
    int* rstart = (int*)w;                 w += ((size_t)(N + 1) * 4 + 255) / 256 * 256;
    int* cursor = (int*)w;                 w += ((size_t)N * 4 + 255) / 256 * 256;
    int* eord   = (int*)w;

    hipMemsetAsync(counts, 0, (size_t)N * sizeof(int), stream);

    vconv_kernel<<<1024, 256, 0, stream>>>(v, Vb, N * H3 / 4);
    node_mlp_kernel<<<(N + NPB - 1) / NPB, 128, 0, stream>>>(s, W1, b1, W2, b2, P, N);
    hist_kernel<<<(E + 255) / 256, 256, 0, stream>>>(eidx, counts, E);
    scan_kernel<<<1, 1024, 0, stream>>>(counts, rstart, cursor, N);
    scatter_kernel<<<(E + 255) / 256, 256, 0, stream>>>(eidx, cursor, eord, E);
    reduce_kernel<<<N, 128, 0, stream>>>(rstart, eord, rbf, cut, evec, Wr, br, P, Vb,
                                         eidx, ds, dv, E);
}